// Round 1
// baseline (30.421 us; speedup 1.0000x reference)
//
#include <hip/hip_runtime.h>
#include <math.h>

#define EPSF 1e-8f
#define INV_SQRT2F 0.70710678118654752f
#define INV_SQRT_2PIF 0.39894228040143268f

__device__ inline void max_gauss(float m1, float v1, float m2, float v2,
                                 float& mo, float& vo) {
    float alpha = sqrtf(v1 + v2 + EPSF);
    float beta  = (m1 - m2) / alpha;
    float e     = erff(beta * INV_SQRT2F);
    float cdf_b  = 0.5f * (1.0f + e);
    float cdf_nb = 0.5f * (1.0f - e);
    float pdf_b  = expf(-0.5f * beta * beta) * INV_SQRT_2PIF;
    mo = m1 * cdf_b + m2 * cdf_nb + alpha * pdf_b;
    vo = (v1 + m1 * m1) * cdf_b + (v2 + m2 * m2) * cdf_nb
       + (m1 + m2) * alpha * pdf_b - mo * mo + EPSF;
}

// x: (32, 2, 128, 64, 64) f32; out: (32, 2, 128, 32, 32) f32
// Block = (b, i): 1024 blocks x 256 threads.
// thread = (g = tid>>5 channel-group, j = tid&31 output col)
__global__ __launch_bounds__(256) void dmp_kernel(const float* __restrict__ x,
                                                  float* __restrict__ out) {
    const int C = 128;
    const size_t CH = 4096; // 64*64 plane

    int blk = blockIdx.x;
    int b = blk >> 5;
    int i = blk & 31;
    int t = threadIdx.x;
    int j = t & 31;
    int g = t >> 5;

    // accumulators: m00 m01 m10 m11 v00 v01 v10 v11
    float a[8] = {0.f, 0.f, 0.f, 0.f, 0.f, 0.f, 0.f, 0.f};

    const float* mbase = x + ((size_t)b * 2) * C * CH + (size_t)(g * 16) * CH
                           + (size_t)(2 * i) * 64 + (size_t)(2 * j);
    const float* vbase = mbase + (size_t)C * CH;

    #pragma unroll 4
    for (int c = 0; c < 16; ++c) {
        const float* mp = mbase + (size_t)c * CH;
        const float* vp = vbase + (size_t)c * CH;
        float2 m0 = *(const float2*)(mp);
        float2 m1 = *(const float2*)(mp + 64);
        float2 v0 = *(const float2*)(vp);
        float2 v1 = *(const float2*)(vp + 64);
        a[0] += m0.x; a[1] += m0.y; a[2] += m1.x; a[3] += m1.y;
        a[4] += v0.x; a[5] += v0.y; a[6] += v1.x; a[7] += v1.y;
    }

    __shared__ float red[8][32][9];  // pad 9 -> conflict-free column reads
    #pragma unroll
    for (int q = 0; q < 8; ++q) red[g][j][q] = a[q];
    __syncthreads();

    __shared__ float mv[2][32];
    if (t < 32) {
        float s[8];
        #pragma unroll
        for (int q = 0; q < 8; ++q) {
            float acc = 0.f;
            #pragma unroll
            for (int gg = 0; gg < 8; ++gg) acc += red[gg][t][q];
            s[q] = acc;
        }
        float hm1, hv1, hm2, hv2, m, v;
        max_gauss(s[0], s[4], s[1], s[5], hm1, hv1);
        max_gauss(s[2], s[6], s[3], s[7], hm2, hv2);
        max_gauss(hm1, hv1, hm2, hv2, m, v);
        mv[0][t] = m;
        mv[1][t] = v;
    }
    __syncthreads();

    // Output: out[((b*2+u)*128 + c)*1024 + i*32 + jj], broadcast over c.
    // 8192 floats = 2048 float4 per block; 8 iterations of 256 threads.
    #pragma unroll
    for (int it = 0; it < 8; ++it) {
        int idx = it * 256 + t;        // 0..2047
        int u   = idx >> 10;           // 0: mean, 1: var
        int rem = idx & 1023;
        int c   = rem >> 3;
        int jq  = rem & 7;             // float4 index within 32-wide row
        float4 val;
        val.x = mv[u][jq * 4 + 0];
        val.y = mv[u][jq * 4 + 1];
        val.z = mv[u][jq * 4 + 2];
        val.w = mv[u][jq * 4 + 3];
        size_t off = (((size_t)b * 2 + u) * C + c) * 1024 + (size_t)i * 32
                   + (size_t)(jq * 4);
        *(float4*)(out + off) = val;
    }
}

extern "C" void kernel_launch(void* const* d_in, const int* in_sizes, int n_in,
                              void* d_out, int out_size, void* d_ws, size_t ws_size,
                              hipStream_t stream) {
    const float* x = (const float*)d_in[0];
    float* out = (float*)d_out;
    dim3 grid(1024), block(256);
    hipLaunchKernelGGL(dmp_kernel, grid, block, 0, stream, x, out);
}